// Round 1
// baseline (132.591 us; speedup 1.0000x reference)
//
#include <hip/hip_runtime.h>

#define N 8000
#define SEQ 200
#define MAX_STEPS 199

// -------------------------------------------------------------------------
// K1: zero the output accumulator; gather D[t][i] = s_t*pe[a_t][a_i]
//     + (1-s_t)*ne[a_t][a_i] into workspace (199*199 floats).
// -------------------------------------------------------------------------
__global__ void k_init_gather(const int* __restrict__ a,
                              const float* __restrict__ s,
                              const float* __restrict__ pe,
                              const float* __restrict__ ne,
                              float* __restrict__ D, int useD,
                              float* __restrict__ out) {
    if (blockIdx.x == 0 && threadIdx.x == 0) out[0] = 0.0f;
    if (!useD) return;

    __shared__ int   sa[MAX_STEPS];
    __shared__ float ss[MAX_STEPS];
    for (int i = threadIdx.x; i < MAX_STEPS; i += blockDim.x) {
        sa[i] = a[i];
        ss[i] = s[i];
    }
    __syncthreads();

    int idx = blockIdx.x * blockDim.x + threadIdx.x;
    const int total = MAX_STEPS * MAX_STEPS;
    if (idx < total) {
        int t = idx / MAX_STEPS;
        int i = idx - t * MAX_STEPS;
        float st = ss[t];
        size_t off = (size_t)sa[t] * N + (size_t)sa[i];
        float d = st * pe[off] + (1.0f - st) * ne[off];
        D[idx] = d;
    }
}

// -------------------------------------------------------------------------
// K2: regularizer  0.5 * sum(log(|pe|+1) + log(|ne|+1))  -> atomicAdd(out)
//     Streams 512 MB; HBM-bound.
// -------------------------------------------------------------------------
__global__ void k_reg(const float* __restrict__ pe,
                      const float* __restrict__ ne,
                      float* __restrict__ out) {
    const size_t NN4 = (size_t)N * N / 4;   // 16M float4 per matrix
    float acc = 0.0f;
    size_t stride = (size_t)gridDim.x * blockDim.x;
    for (size_t p = (size_t)blockIdx.x * blockDim.x + threadIdx.x; p < NN4;
         p += stride) {
        float4 v = ((const float4*)pe)[p];
        float4 w = ((const float4*)ne)[p];
        acc += __logf(fabsf(v.x) + 1.0f);
        acc += __logf(fabsf(v.y) + 1.0f);
        acc += __logf(fabsf(v.z) + 1.0f);
        acc += __logf(fabsf(v.w) + 1.0f);
        acc += __logf(fabsf(w.x) + 1.0f);
        acc += __logf(fabsf(w.y) + 1.0f);
        acc += __logf(fabsf(w.z) + 1.0f);
        acc += __logf(fabsf(w.w) + 1.0f);
    }
    // wave64 reduce
    #pragma unroll
    for (int o = 32; o > 0; o >>= 1) acc += __shfl_down(acc, o);
    __shared__ float wsum[4];
    int lane = threadIdx.x & 63;
    int wid  = threadIdx.x >> 6;
    if (lane == 0) wsum[wid] = acc;
    __syncthreads();
    if (threadIdx.x == 0) {
        float b = wsum[0] + wsum[1] + wsum[2] + wsum[3];
        atomicAdd(out, 0.5f * b);
    }
}

// -------------------------------------------------------------------------
// K3: sequential loss. Thread i (i < 199) clip-folds its column of D over
//     t = 0..i-1, computes the NLL term for step i, block-reduce, add to out.
// -------------------------------------------------------------------------
__global__ void k_loss(const int* __restrict__ a,
                       const float* __restrict__ s,
                       const float* __restrict__ pe,
                       const float* __restrict__ ne,
                       const float* __restrict__ kp,
                       const float* __restrict__ D, int useD,
                       float* __restrict__ out) {
    __shared__ int   sa[MAX_STEPS];
    __shared__ float ss[MAX_STEPS];
    int tid = threadIdx.x;
    for (int i = tid; i < MAX_STEPS; i += blockDim.x) {
        sa[i] = a[i];
        ss[i] = s[i];
    }
    __syncthreads();

    // V = first step with s < 0 (prefix-validity cutoff), else MAX_STEPS
    __shared__ int V;
    if (tid == 0) {
        int v = MAX_STEPS;
        for (int t = 0; t < MAX_STEPS; ++t) {
            if (ss[t] < 0.0f) { v = t; break; }
        }
        V = v;
    }
    __syncthreads();

    float li = 0.0f;
    if (tid < MAX_STEPS && tid < V) {
        int j = sa[tid];
        float k = kp[j];
        if (useD) {
            int t = 0;
            for (; t + 8 <= tid; t += 8) {
                float d[8];
                #pragma unroll
                for (int u = 0; u < 8; ++u) d[u] = D[(t + u) * MAX_STEPS + tid];
                #pragma unroll
                for (int u = 0; u < 8; ++u)
                    k = fminf(fmaxf(k + d[u], -30.0f), 30.0f);
            }
            for (; t < tid; ++t) {
                float d = D[t * MAX_STEPS + tid];
                k = fminf(fmaxf(k + d, -30.0f), 30.0f);
            }
        } else {
            for (int t = 0; t < tid; ++t) {
                float st = ss[t];
                size_t off = (size_t)sa[t] * N + (size_t)j;
                float d = st * pe[off] + (1.0f - st) * ne[off];
                k = fminf(fmaxf(k + d, -30.0f), 30.0f);
            }
        }
        float p = fminf(fmaxf(k, 0.01f), 0.99f);
        li = -(ss[tid] * logf(p) + (1.0f - ss[tid]) * logf(1.0f - p));
    }

    // block reduce (256 threads; inactive lanes contribute 0)
    #pragma unroll
    for (int o = 32; o > 0; o >>= 1) li += __shfl_down(li, o);
    __shared__ float wsum[4];
    int lane = tid & 63;
    int wid  = tid >> 6;
    if (lane == 0) wsum[wid] = li;
    __syncthreads();
    if (tid == 0) {
        float total = wsum[0] + wsum[1] + wsum[2] + wsum[3];
        atomicAdd(out, total);
    }
}

extern "C" void kernel_launch(void* const* d_in, const int* in_sizes, int n_in,
                              void* d_out, int out_size, void* d_ws, size_t ws_size,
                              hipStream_t stream) {
    const int*   a  = (const int*)d_in[0];
    const float* s  = (const float*)d_in[1];
    const float* pe = (const float*)d_in[2];
    const float* ne = (const float*)d_in[3];
    const float* kp = (const float*)d_in[4];
    float* out = (float*)d_out;

    float* D = (float*)d_ws;
    int useD = (ws_size >= sizeof(float) * MAX_STEPS * MAX_STEPS) ? 1 : 0;

    const int gatherBlocks = (MAX_STEPS * MAX_STEPS + 255) / 256;
    k_init_gather<<<gatherBlocks, 256, 0, stream>>>(a, s, pe, ne, D, useD, out);
    k_reg<<<2048, 256, 0, stream>>>(pe, ne, out);
    k_loss<<<1, 256, 0, stream>>>(a, s, pe, ne, kp, D, useD, out);
}

// Round 2
// 123.308 us; speedup vs baseline: 1.0753x; 1.0753x over previous
//
#include <hip/hip_runtime.h>

#define N 8000
#define SEQ 200
#define MAX_STEPS 199

#define REG_BLOCKS 2048
#define REG_THREADS 256
#define REG_TOTAL (REG_BLOCKS * REG_THREADS)          // 524288
// NN4 = N*N/4 = 16,000,000 float4 per matrix
#define NN4 16000000
#define NFULL 30                                       // 30*524288 = 15,728,640 <= NN4

// -------------------------------------------------------------------------
// K1: zero the output accumulator; gather D[t][i] = s_t*pe[a_t][a_i]
//     + (1-s_t)*ne[a_t][a_i] into workspace (199*199 floats).
// -------------------------------------------------------------------------
__global__ void k_init_gather(const int* __restrict__ a,
                              const float* __restrict__ s,
                              const float* __restrict__ pe,
                              const float* __restrict__ ne,
                              float* __restrict__ D, int useD,
                              float* __restrict__ out) {
    if (blockIdx.x == 0 && threadIdx.x == 0) out[0] = 0.0f;
    if (!useD) return;

    __shared__ int   sa[MAX_STEPS];
    __shared__ float ss[MAX_STEPS];
    for (int i = threadIdx.x; i < MAX_STEPS; i += blockDim.x) {
        sa[i] = a[i];
        ss[i] = s[i];
    }
    __syncthreads();

    int idx = blockIdx.x * blockDim.x + threadIdx.x;
    const int total = MAX_STEPS * MAX_STEPS;
    if (idx < total) {
        int t = idx / MAX_STEPS;
        int i = idx - t * MAX_STEPS;
        float st = ss[t];
        size_t off = (size_t)sa[t] * N + (size_t)sa[i];
        float d = st * pe[off] + (1.0f - st) * ne[off];
        D[idx] = d;
    }
}

// -------------------------------------------------------------------------
// K2: regularizer  0.5 * sum(log(|pe|+1) + log(|ne|+1))  -> atomicAdd(out)
//     log(|x|+1) = ln2 * log2(|x|+1); v_log_f32 IS log2 -> 3 VALU/elem.
//     ln2*0.5 applied once per block at the atomic.
// -------------------------------------------------------------------------
__global__ void __launch_bounds__(REG_THREADS)
k_reg(const float* __restrict__ pe,
      const float* __restrict__ ne,
      float* __restrict__ out) {
    const float4* __restrict__ pe4 = (const float4*)pe;
    const float4* __restrict__ ne4 = (const float4*)ne;
    const int tid0 = blockIdx.x * REG_THREADS + threadIdx.x;

    float acc = 0.0f;
    // 30 full strides: trip count is compile-time, no bound checks.
    #pragma unroll 2
    for (int k = 0; k < NFULL; ++k) {
        size_t p = (size_t)tid0 + (size_t)k * REG_TOTAL;
        float4 v = pe4[p];
        float4 w = ne4[p];
        acc += __log2f(fabsf(v.x) + 1.0f);
        acc += __log2f(fabsf(v.y) + 1.0f);
        acc += __log2f(fabsf(v.z) + 1.0f);
        acc += __log2f(fabsf(v.w) + 1.0f);
        acc += __log2f(fabsf(w.x) + 1.0f);
        acc += __log2f(fabsf(w.y) + 1.0f);
        acc += __log2f(fabsf(w.z) + 1.0f);
        acc += __log2f(fabsf(w.w) + 1.0f);
    }
    // guarded tail stride
    {
        size_t p = (size_t)tid0 + (size_t)NFULL * REG_TOTAL;
        if (p < (size_t)NN4) {
            float4 v = pe4[p];
            float4 w = ne4[p];
            acc += __log2f(fabsf(v.x) + 1.0f);
            acc += __log2f(fabsf(v.y) + 1.0f);
            acc += __log2f(fabsf(v.z) + 1.0f);
            acc += __log2f(fabsf(v.w) + 1.0f);
            acc += __log2f(fabsf(w.x) + 1.0f);
            acc += __log2f(fabsf(w.y) + 1.0f);
            acc += __log2f(fabsf(w.z) + 1.0f);
            acc += __log2f(fabsf(w.w) + 1.0f);
        }
    }

    // wave64 reduce
    #pragma unroll
    for (int o = 32; o > 0; o >>= 1) acc += __shfl_down(acc, o);
    __shared__ float wsum[REG_THREADS / 64];
    int lane = threadIdx.x & 63;
    int wid  = threadIdx.x >> 6;
    if (lane == 0) wsum[wid] = acc;
    __syncthreads();
    if (threadIdx.x == 0) {
        float b = 0.0f;
        #pragma unroll
        for (int w = 0; w < REG_THREADS / 64; ++w) b += wsum[w];
        // 0.5 * ln(2) folded here (log2 -> ln conversion)
        atomicAdd(out, 0.34657359027997264f * b);
    }
}

// -------------------------------------------------------------------------
// K3: sequential loss. Thread i (i < 199) clip-folds its column of D over
//     t = 0..i-1, computes the NLL term for step i, block-reduce, add to out.
// -------------------------------------------------------------------------
__global__ void k_loss(const int* __restrict__ a,
                       const float* __restrict__ s,
                       const float* __restrict__ pe,
                       const float* __restrict__ ne,
                       const float* __restrict__ kp,
                       const float* __restrict__ D, int useD,
                       float* __restrict__ out) {
    __shared__ int   sa[MAX_STEPS];
    __shared__ float ss[MAX_STEPS];
    int tid = threadIdx.x;
    for (int i = tid; i < MAX_STEPS; i += blockDim.x) {
        sa[i] = a[i];
        ss[i] = s[i];
    }
    __syncthreads();

    // V = first step with s < 0 (prefix-validity cutoff), else MAX_STEPS
    __shared__ int V;
    if (tid == 0) {
        int v = MAX_STEPS;
        for (int t = 0; t < MAX_STEPS; ++t) {
            if (ss[t] < 0.0f) { v = t; break; }
        }
        V = v;
    }
    __syncthreads();

    float li = 0.0f;
    if (tid < MAX_STEPS && tid < V) {
        int j = sa[tid];
        float k = kp[j];
        if (useD) {
            int t = 0;
            for (; t + 8 <= tid; t += 8) {
                float d[8];
                #pragma unroll
                for (int u = 0; u < 8; ++u) d[u] = D[(t + u) * MAX_STEPS + tid];
                #pragma unroll
                for (int u = 0; u < 8; ++u)
                    k = fminf(fmaxf(k + d[u], -30.0f), 30.0f);
            }
            for (; t < tid; ++t) {
                float d = D[t * MAX_STEPS + tid];
                k = fminf(fmaxf(k + d, -30.0f), 30.0f);
            }
        } else {
            for (int t = 0; t < tid; ++t) {
                float st = ss[t];
                size_t off = (size_t)sa[t] * N + (size_t)j;
                float d = st * pe[off] + (1.0f - st) * ne[off];
                k = fminf(fmaxf(k + d, -30.0f), 30.0f);
            }
        }
        float p = fminf(fmaxf(k, 0.01f), 0.99f);
        li = -(ss[tid] * logf(p) + (1.0f - ss[tid]) * logf(1.0f - p));
    }

    // block reduce (256 threads; inactive lanes contribute 0)
    #pragma unroll
    for (int o = 32; o > 0; o >>= 1) li += __shfl_down(li, o);
    __shared__ float wsum[4];
    int lane = tid & 63;
    int wid  = tid >> 6;
    if (lane == 0) wsum[wid] = li;
    __syncthreads();
    if (tid == 0) {
        float total = wsum[0] + wsum[1] + wsum[2] + wsum[3];
        atomicAdd(out, total);
    }
}

extern "C" void kernel_launch(void* const* d_in, const int* in_sizes, int n_in,
                              void* d_out, int out_size, void* d_ws, size_t ws_size,
                              hipStream_t stream) {
    const int*   a  = (const int*)d_in[0];
    const float* s  = (const float*)d_in[1];
    const float* pe = (const float*)d_in[2];
    const float* ne = (const float*)d_in[3];
    const float* kp = (const float*)d_in[4];
    float* out = (float*)d_out;

    float* D = (float*)d_ws;
    int useD = (ws_size >= sizeof(float) * MAX_STEPS * MAX_STEPS) ? 1 : 0;

    const int gatherBlocks = (MAX_STEPS * MAX_STEPS + 255) / 256;
    k_init_gather<<<gatherBlocks, 256, 0, stream>>>(a, s, pe, ne, D, useD, out);
    k_reg<<<REG_BLOCKS, REG_THREADS, 0, stream>>>(pe, ne, out);
    k_loss<<<1, 256, 0, stream>>>(a, s, pe, ne, kp, D, useD, out);
}